// Round 2
// baseline (489.855 us; speedup 1.0000x reference)
//
#include <hip/hip_runtime.h>

#define N_TOK 16384
#define N_EMB 8192
#define DIM   512
#define KSPLIT 4
#define KB    (N_EMB / KSPLIT)   // 2048 codes per y-block

typedef __attribute__((ext_vector_type(8))) short bf16x8;
typedef __attribute__((ext_vector_type(16))) float f32x16;
typedef __attribute__((ext_vector_type(4))) unsigned short u16x4;
typedef unsigned short u16;

__device__ __forceinline__ u16 f2bf(float f) {
    unsigned u = __float_as_uint(f);
    u += 0x7fffu + ((u >> 16) & 1u);
    return (u16)(u >> 16);
}
__device__ __forceinline__ float bf2f(u16 h) {
    return __uint_as_float(((unsigned)h) << 16);
}

__device__ __forceinline__ void gload16(const void* g, void* l) {
    __builtin_amdgcn_global_load_lds(
        (const __attribute__((address_space(1))) unsigned int*)g,
        (__attribute__((address_space(3))) unsigned int*)l, 16, 0, 0);
}

// ---------------- prep: split x into bf16 hi/lo ----------------
__global__ void prep_x_kernel(const float* __restrict__ x,
                              u16* __restrict__ xhi, u16* __restrict__ xlo) {
    int i = (blockIdx.x * 256 + threadIdx.x) * 4;
    float4 v = *(const float4*)(x + i);
    u16x4 h, l;
    h.x = f2bf(v.x); l.x = f2bf(v.x - bf2f(h.x));
    h.y = f2bf(v.y); l.y = f2bf(v.y - bf2f(h.y));
    h.z = f2bf(v.z); l.z = f2bf(v.z - bf2f(h.z));
    h.w = f2bf(v.w); l.w = f2bf(v.w - bf2f(h.w));
    *(u16x4*)(xhi + i) = h;
    *(u16x4*)(xlo + i) = l;
}

// ---------------- prep: split w + wsq (one wave per row) ----------------
__global__ void prep_w_kernel(const float* __restrict__ w,
                              u16* __restrict__ whi, u16* __restrict__ wlo,
                              float* __restrict__ wsq) {
    const int tid = threadIdx.x, lane = tid & 63, wv = tid >> 6;
    const int row = blockIdx.x * 4 + wv;
    const float* src = w + (size_t)row * DIM;
    float s = 0.f;
#pragma unroll
    for (int j = 0; j < 2; ++j) {
        int d = j * 256 + lane * 4;
        float4 v = *(const float4*)(src + d);
        u16x4 h, l;
        h.x = f2bf(v.x); l.x = f2bf(v.x - bf2f(h.x));
        h.y = f2bf(v.y); l.y = f2bf(v.y - bf2f(h.y));
        h.z = f2bf(v.z); l.z = f2bf(v.z - bf2f(h.z));
        h.w = f2bf(v.w); l.w = f2bf(v.w - bf2f(h.w));
        *(u16x4*)(whi + (size_t)row * DIM + d) = h;
        *(u16x4*)(wlo + (size_t)row * DIM + d) = l;
        s += v.x * v.x + v.y * v.y + v.z * v.z + v.w * v.w;
    }
#pragma unroll
    for (int off = 1; off < 64; off <<= 1) s += __shfl_xor(s, off);
    if (lane == 0) wsq[row] = s;
}

// ---------------- main: 3-pass split-bf16 GEMM (32x32x16) + streaming argmin ----------------
// LDS per buffer: 4 planes (xhi,xlo,whi,wlo) of [128 rows][32 dims] bf16.
// Swizzle: element (r,k) at byte r*64 + ((2k) ^ (((r>>1)&3)<<4)).
// Double-buffered: 2 x 32 KiB = 64 KiB -> 2 blocks/CU.
#define MFMA3(d, ah, al, bh, bl)                                              \
    d = __builtin_amdgcn_mfma_f32_32x32x16_bf16(ah, bh, d, 0, 0, 0);          \
    d = __builtin_amdgcn_mfma_f32_32x32x16_bf16(ah, bl, d, 0, 0, 0);          \
    d = __builtin_amdgcn_mfma_f32_32x32x16_bf16(al, bh, d, 0, 0, 0);

__global__ __launch_bounds__(256, 2)
void gemm_argmin_kernel(const u16* __restrict__ xhi, const u16* __restrict__ xlo,
                        const u16* __restrict__ whi, const u16* __restrict__ wlo,
                        const float* __restrict__ wsq,
                        float* __restrict__ wsval, int* __restrict__ wsidx) {
    __shared__ u16 sm[2][4][128 * 32];   // 64 KiB
    const int tid = threadIdx.x;
    const int lane = tid & 63, wv = tid >> 6;
    const int wm = wv >> 1, wn = wv & 1;
    const int RB = blockIdx.x * 128;
    const int CB = blockIdx.y * KB;

    // staging address pieces (gload_lds dest is base + lane*16, linear):
    // lane l feeds row r = seg*16 + (l>>2), linear 16B granule (l&3);
    // data there must be source chunk (l&3) ^ ((r>>1)&3) = (l&3) ^ ((l>>3)&3).
    const int srow = lane >> 2;
    const int srcoff = (((lane & 3) ^ ((lane >> 3) & 3)) << 3);

    float runv[32];
    int   runi[32];
#pragma unroll
    for (int e = 0; e < 32; ++e) { runv[e] = 3.4e38f; runi[e] = 0; }

    // read-side offsets (wave-constant parts)
    const int rA = wm * 64 + (lane & 31);
    const int rB = wn * 64 + (lane & 31);
    const int swzA = ((rA >> 1) & 3) << 4;
    const int swzB = ((rB >> 1) & 3) << 4;
    const int khalf = (lane >> 5) * 16;

    auto stage = [&](int buf, int t) {
        const int cb = CB + (t >> 4) * 128;
        const int d0 = (t & 15) * 32;
#pragma unroll
        for (int j = 0; j < 2; ++j) {
            int seg = wv + j * 4;                 // wave-uniform
            int r = seg * 16 + srow;
            size_t soX = (size_t)(RB + r) * DIM + d0 + srcoff;
            size_t soW = (size_t)(cb + r) * DIM + d0 + srcoff;
            gload16(xhi + soX, &sm[buf][0][seg * 512]);
            gload16(xlo + soX, &sm[buf][1][seg * 512]);
            gload16(whi + soW, &sm[buf][2][seg * 512]);
            gload16(wlo + soW, &sm[buf][3][seg * 512]);
        }
    };

    stage(0, 0);
    __syncthreads();          // prologue drain (once)

    f32x16 a00, a01, a10, a11;
    int buf = 0;
    for (int t = 0; t < 256; ++t) {
        stage(buf ^ 1, (t + 1) & 255);   // issue-early; lands during compute

        if ((t & 15) == 0) {
#pragma unroll
            for (int r = 0; r < 16; ++r) { a00[r] = 0.f; a01[r] = 0.f; a10[r] = 0.f; a11[r] = 0.f; }
        }

        const char* base = (const char*)&sm[buf][0][0];
#pragma unroll
        for (int kk = 0; kk < 2; ++kk) {
            const int cA = (kk * 32 + khalf) ^ swzA;
            const int cB = (kk * 32 + khalf) ^ swzB;
            const int offA = rA * 64 + cA;
            const int offB = rB * 64 + cB;
            bf16x8 ah0 = *(const bf16x8*)(base + offA);
            bf16x8 ah1 = *(const bf16x8*)(base + offA + 2048);
            bf16x8 al0 = *(const bf16x8*)(base + 8192 + offA);
            bf16x8 al1 = *(const bf16x8*)(base + 8192 + offA + 2048);
            bf16x8 bh0 = *(const bf16x8*)(base + 16384 + offB);
            bf16x8 bh1 = *(const bf16x8*)(base + 16384 + offB + 2048);
            bf16x8 bl0 = *(const bf16x8*)(base + 24576 + offB);
            bf16x8 bl1 = *(const bf16x8*)(base + 24576 + offB + 2048);
            __builtin_amdgcn_s_setprio(1);
            MFMA3(a00, ah0, al0, bh0, bl0);
            MFMA3(a01, ah0, al0, bh1, bl1);
            MFMA3(a10, ah1, al1, bh0, bl0);
            MFMA3(a11, ah1, al1, bh1, bl1);
            __builtin_amdgcn_s_setprio(0);
        }

        if ((t & 15) == 15) {
            // epilogue for this 128-code chunk: score = wsq - 2*S
            const int cb = CB + (t >> 4) * 128;
            const int c0 = cb + wn * 64 + (lane & 31);
            const float wq0 = wsq[c0];
            const float wq1 = wsq[c0 + 32];
#pragma unroll
            for (int r = 0; r < 16; ++r) {
                float s0 = wq0 - 2.0f * a00[r];
                if (s0 < runv[r])      { runv[r] = s0;      runi[r] = c0; }
                float s1 = wq1 - 2.0f * a01[r];
                if (s1 < runv[r])      { runv[r] = s1;      runi[r] = c0 + 32; }
                float s2 = wq0 - 2.0f * a10[r];
                if (s2 < runv[16 + r]) { runv[16 + r] = s2; runi[16 + r] = c0; }
                float s3 = wq1 - 2.0f * a11[r];
                if (s3 < runv[16 + r]) { runv[16 + r] = s3; runi[16 + r] = c0 + 32; }
            }
        }
        __syncthreads();     // drains staging (cheap: latency already hidden)
        buf ^= 1;
    }

    // cross-lane reduce: lanes 0..31 / 32..63 hold disjoint row sets (hi = lane>>5);
    // reduce over the 32 columns (lane&31) per half.
    float* mv  = (float*)&sm[0][0][0];                 // [2][128]
    int*   mi_ = (int*)((char*)&sm[0][0][0] + 1024);   // [2][128]
    const int hi = lane >> 5;
#pragma unroll
    for (int e = 0; e < 32; ++e) {
        float v = runv[e];
        int   ix = runi[e];
#pragma unroll
        for (int off = 1; off < 32; off <<= 1) {
            float ov = __shfl_xor(v, off);
            int   oi = __shfl_xor(ix, off);
            if (ov < v || (ov == v && oi < ix)) { v = ov; ix = oi; }
        }
        if ((lane & 31) == 0) {
            int mi2 = e >> 4, rr = e & 15;
            int rl = wm * 64 + mi2 * 32 + (rr & 3) + 8 * (rr >> 2) + 4 * hi;
            mv[wn * 128 + rl]  = v;
            mi_[wn * 128 + rl] = ix;
        }
    }
    __syncthreads();
    if (tid < 128) {
        float v0 = mv[tid];       int i0 = mi_[tid];
        float v1 = mv[128 + tid]; int i1 = mi_[128 + tid];
        if (v1 < v0 || (v1 == v0 && i1 < i0)) { v0 = v1; i0 = i1; }
        wsval[(size_t)(RB + tid) * KSPLIT + blockIdx.y] = v0;
        wsidx[(size_t)(RB + tid) * KSPLIT + blockIdx.y] = i0;
    }
}

// ---------------- merge ksplits + gather + loss partials ----------------
__global__ void gather_loss_kernel(const float* __restrict__ w, const float* __restrict__ x,
                                   const float* __restrict__ wsval, const int* __restrict__ wsidx,
                                   float* __restrict__ out, float* __restrict__ lossp) {
    const int tid = threadIdx.x, lane = tid & 63, wv = tid >> 6;
    const int t = blockIdx.x * 4 + wv;
    int bi = 0;
    if (lane == 0) {
        float bv = wsval[(size_t)t * KSPLIT];
        bi = wsidx[(size_t)t * KSPLIT];
#pragma unroll
        for (int ks = 1; ks < KSPLIT; ++ks) {
            float v = wsval[(size_t)t * KSPLIT + ks];
            int  ix = wsidx[(size_t)t * KSPLIT + ks];
            if (v < bv || (v == bv && ix < bi)) { bv = v; bi = ix; }
        }
    }
    bi = __shfl(bi, 0);
    const float* wr = w + (size_t)bi * DIM;
    const float* xr = x + (size_t)t * DIM;
    float* orow = out + (size_t)t * DIM;
    float s = 0.f;
#pragma unroll
    for (int j = 0; j < 2; ++j) {
        int d = j * 256 + lane * 4;
        float4 a = *(const float4*)(wr + d);
        float4 b = *(const float4*)(xr + d);
        *(float4*)(orow + d) = a;
        float d0 = a.x - b.x, d1 = a.y - b.y, d2 = a.z - b.z, d3 = a.w - b.w;
        s += d0 * d0 + d1 * d1 + d2 * d2 + d3 * d3;
    }
#pragma unroll
    for (int off = 1; off < 64; off <<= 1) s += __shfl_xor(s, off);
    __shared__ float ls[4];
    if (lane == 0) ls[wv] = s;
    __syncthreads();
    if (tid == 0) lossp[blockIdx.x] = ls[0] + ls[1] + ls[2] + ls[3];
}

// ---------------- deterministic final loss reduce ----------------
__global__ void loss_final_kernel(const float* __restrict__ lossp, float* __restrict__ out) {
    __shared__ float red[256];
    float s = 0.f;
    for (int i = threadIdx.x; i < N_TOK / 4; i += 256) s += lossp[i];
    red[threadIdx.x] = s;
    __syncthreads();
    for (int st = 128; st > 0; st >>= 1) {
        if (threadIdx.x < st) red[threadIdx.x] += red[threadIdx.x + st];
        __syncthreads();
    }
    // vq_loss = (1 + BETA) * mean((q - x)^2)
    if (threadIdx.x == 0) out[(size_t)N_TOK * DIM] = red[0] * (1.25f / 8388608.f);
}

extern "C" void kernel_launch(void* const* d_in, const int* in_sizes, int n_in,
                              void* d_out, int out_size, void* d_ws, size_t ws_size,
                              hipStream_t stream) {
    const float* x = (const float*)d_in[0];   // [16384,512]
    const float* w = (const float*)d_in[1];   // [8192,512]
    float* out = (float*)d_out;               // 16384*512 + 1

    char* W = (char*)d_ws;
    u16*   xhi   = (u16*)(W);                        // 16 MiB
    u16*   xlo   = (u16*)(W + 16777216);             // 16 MiB
    u16*   whi   = (u16*)(W + 33554432);             // 8 MiB
    u16*   wlo   = (u16*)(W + 41943040);             // 8 MiB
    float* wsq   = (float*)(W + 50331648);           // 32 KiB
    float* wsval = (float*)(W + 50364416);           // 256 KiB
    int*   wsidx = (int*)  (W + 50626560);           // 256 KiB
    float* lossp = (float*)(W + 50888704);           // 16 KiB

    prep_x_kernel<<<N_TOK * DIM / 1024, 256, 0, stream>>>(x, xhi, xlo);
    prep_w_kernel<<<N_EMB / 4, 256, 0, stream>>>(w, whi, wlo, wsq);
    dim3 g(N_TOK / 128, KSPLIT);
    gemm_argmin_kernel<<<g, 256, 0, stream>>>(xhi, xlo, whi, wlo, wsq, wsval, wsidx);
    gather_loss_kernel<<<N_TOK / 4, 256, 0, stream>>>(w, x, wsval, wsidx, out, lossp);
    loss_final_kernel<<<1, 256, 0, stream>>>(lossp, out);
}